// Round 1
// 352.192 us; speedup vs baseline: 1.0169x; 1.0169x over previous
//
#include <hip/hip_runtime.h>
#include <math.h>

// ---------------------------------------------------------------------------
// HDRNet, N=4, low 256x256, full 1024x1024. 8-launch pipeline (R7):
//   conv0, conv1 (thread-per-output, unrolled), conv2, conv3 (split-K)
//   k5: l0 + g1 + splat-means | k6: l1 + g2 + x1-means
//   kfc: redundant-FC + fuse_grid | hdr: 1px/thread v3
// R7 changes vs R6 (hdr was VALU-issue-bound, VALUBusy=66%, Occ=19%, VGPR=128):
//   - hdr_out_v3: 1 pixel/thread (16384 blocks) to shrink per-thread state
//     and raise waves/SIMD from 4 toward 6-8. Same math per pixel.
//   - grid re-layout to z-innermost: grid[n][cell][z][ch] so the 2 z-slices
//     per pixel are contiguous (2x48B in one 384B record) -> 4 cell bases
//     instead of 8 corner addresses, better L1 locality. kfc write updated.
// NOTE: __launch_bounds__(256,4) on hdr forced VGPR 64 -> ~420MB scratch
// spill (R5 regression). Keep plain (256).
// Workspace floats: t0 524288 | t1 262144 | t2 131072 | splat 65536 |
// l0o 65536 | local 65536 | x1 32768 | x2 16384 | avec 1792 | grid 98304
// ---------------------------------------------------------------------------

__device__ __forceinline__ float tanh_fast(float x) {
    float e = __expf(2.0f * x);
    return 1.0f - 2.0f / (e + 1.0f);
}

// ---- small-Cin stride-2 conv, thread-per-output, fully unrolled ----
template<int CIN, int COUT, int HIN, int WIN, int HOUT, int WOUT>
__global__ __launch_bounds__(256) void conv_s2_small(
    const float* __restrict__ in, const float* __restrict__ w,
    const float* __restrict__ b, float* __restrict__ out)
{
    int idx = blockIdx.x * 256 + threadIdx.x;
    int wo = idx % WOUT; int t = idx / WOUT;
    int ho = t % HOUT; t /= HOUT;
    int co = t % COUT; int n = t / COUT;
    float acc = b[co];
    int hi0 = ho * 2 - 1, wi0 = wo * 2 - 1;
    const float* wp = w + (size_t)co * CIN * 9;
    #pragma unroll
    for (int ci = 0; ci < CIN; ++ci) {
        const float* ip = in + ((size_t)(n * CIN + ci)) * HIN * WIN;
        const float* wc = wp + ci * 9;
        #pragma unroll
        for (int kh = 0; kh < 3; ++kh) {
            int hi = hi0 + kh;
            if ((unsigned)hi >= (unsigned)HIN) continue;
            const float* row = ip + hi * WIN;
            #pragma unroll
            for (int kw = 0; kw < 3; ++kw) {
                int wi = wi0 + kw;
                if ((unsigned)wi >= (unsigned)WIN) continue;
                acc = fmaf(wc[kh * 3 + kw], row[wi], acc);
            }
        }
    }
    out[idx] = fmaxf(acc, 0.0f);
}

// ---- PARTS-way input-channel-split 3x3 conv ----
template<int CIN, int PARTS, int STRIDE, bool RELU, bool HASB,
         int COUT, int HIN, int WIN, int HOUT, int WOUT>
__device__ __forceinline__ void conv_p_dev(
    const float* __restrict__ in, const float* __restrict__ w,
    const float* __restrict__ b, float* __restrict__ out,
    int tb, float* red)
{
    constexpr int CPT = CIN / PARTS;
    constexpr int OPB = 256 / PARTS;
    int part = threadIdx.x / OPB;
    int oidx = threadIdx.x % OPB;
    int o = tb * OPB + oidx;
    int wo = o % WOUT; int t = o / WOUT;
    int ho = t % HOUT; t /= HOUT;
    int co = t % COUT; int n = t / COUT;
    int hi0 = ho * STRIDE - 1, wi0 = wo * STRIDE - 1;
    const float* wp = w + ((size_t)co * CIN + part * CPT) * 9;
    const float* ip = in + ((size_t)n * CIN + part * CPT) * HIN * WIN;
    float acc = 0.0f;
    #pragma unroll
    for (int ci = 0; ci < CPT; ++ci) {
        const float* ic = ip + (size_t)ci * HIN * WIN;
        const float* wc = wp + ci * 9;
        #pragma unroll
        for (int kh = 0; kh < 3; ++kh) {
            int hi = hi0 + kh;
            if ((unsigned)hi >= (unsigned)HIN) continue;
            const float* row = ic + hi * WIN;
            #pragma unroll
            for (int kw = 0; kw < 3; ++kw) {
                int wi = wi0 + kw;
                if ((unsigned)wi >= (unsigned)WIN) continue;
                acc = fmaf(wc[kh * 3 + kw], row[wi], acc);
            }
        }
    }
    red[threadIdx.x] = acc;
    __syncthreads();
    if (part == 0) {
        float s = acc;
        #pragma unroll
        for (int p = 1; p < PARTS; ++p) s += red[p * OPB + oidx];
        if (HASB) s += b[co];
        if (RELU) s = fmaxf(s, 0.0f);
        out[o] = s;
    }
}

// conv2: t1(4,16,64,64) -> t2(4,32,32,32)
__global__ __launch_bounds__(256) void conv2_k(
    const float* __restrict__ in, const float* __restrict__ w,
    const float* __restrict__ b, float* __restrict__ out)
{
    __shared__ float red[256];
    conv_p_dev<16, 4, 2, true, true, 32, 64, 64, 32, 32>(in, w, b, out, blockIdx.x, red);
}

// conv3: t2 -> splat(4,64,16,16)
__global__ __launch_bounds__(256) void conv3_k(
    const float* __restrict__ in, const float* __restrict__ w,
    const float* __restrict__ b, float* __restrict__ out)
{
    __shared__ float red[256];
    conv_p_dev<32, 8, 2, true, true, 64, 32, 32, 16, 16>(in, w, b, out, blockIdx.x, red);
}

// k5: l0 (4096 tbs) + g1 (2048 tbs) + splat-means (64 blocks)
__global__ __launch_bounds__(256) void k5_l0_g1_means(
    const float* __restrict__ splat,
    const float* __restrict__ wl0, const float* __restrict__ bl0, float* __restrict__ l0o,
    const float* __restrict__ wg1, const float* __restrict__ bg1, float* __restrict__ x1,
    float* __restrict__ avec)
{
    __shared__ float red[256];
    int bid = blockIdx.x;
    if (bid < 4096) {
        conv_p_dev<64, 16, 1, true, true, 64, 16, 16, 16, 16>(splat, wl0, bl0, l0o, bid, red);
    } else if (bid < 6144) {
        conv_p_dev<64, 16, 2, true, true, 128, 16, 16, 8, 8>(splat, wg1, bg1, x1, bid - 4096, red);
    } else {
        int wid = (bid - 6144) * 4 + (threadIdx.x >> 6);   // 0..255
        int lane = threadIdx.x & 63;
        int n = wid >> 6, c = wid & 63;
        const float* p = splat + ((size_t)(n * 64 + c)) * 256;
        float s = p[lane] + p[lane + 64] + p[lane + 128] + p[lane + 192];
        #pragma unroll
        for (int off = 32; off; off >>= 1) s += __shfl_down(s, off, 64);
        if (lane == 0) avec[n * 448 + c] = s * (1.0f / 256.0f);
    }
}

// k6: l1 (4096 tbs) + g2 (1024 tbs) + x1-means (128 blocks)
__global__ __launch_bounds__(256) void k6_l1_g2_means(
    const float* __restrict__ l0o, const float* __restrict__ wl1, float* __restrict__ localb,
    const float* __restrict__ x1, const float* __restrict__ wg2,
    const float* __restrict__ bg2, float* __restrict__ x2,
    float* __restrict__ avec)
{
    __shared__ float red[256];
    int bid = blockIdx.x;
    if (bid < 4096) {
        conv_p_dev<64, 16, 1, false, false, 64, 16, 16, 16, 16>(l0o, wl1, nullptr, localb, bid, red);
    } else if (bid < 5120) {
        conv_p_dev<128, 16, 2, true, true, 256, 8, 8, 4, 4>(x1, wg2, bg2, x2, bid - 4096, red);
    } else {
        int wid = (bid - 5120) * 4 + (threadIdx.x >> 6);   // 0..511
        int lane = threadIdx.x & 63;
        int n = wid >> 7, c = wid & 127;
        const float* p = x1 + ((size_t)(n * 128 + c)) * 64;
        float s = p[lane];
        #pragma unroll
        for (int off = 32; off; off >>= 1) s += __shfl_down(s, off, 64);
        if (lane == 0) avec[n * 448 + 64 + c] = s * (1.0f / 64.0f);
    }
}

// kfc: per-block redundant FC chain (448->256->128->64 in LDS) + fuse_grid.
// R7: grid stored z-INNERMOST: grid[n*24576 + cell*96 + z*12 + ch]
// so hdr's two z-slices per pixel are contiguous (2x48B within 384B record).
__global__ __launch_bounds__(256) void kfc_fuse(
    const float* __restrict__ avec, const float* __restrict__ x2,
    const float* __restrict__ wf1, const float* __restrict__ bf1,
    const float* __restrict__ wf2, const float* __restrict__ bf2,
    const float* __restrict__ wf3, const float* __restrict__ bf3,
    const float* __restrict__ local,
    const float* __restrict__ wlin, const float* __restrict__ blin,
    float* __restrict__ grid)
{
    __shared__ float a[448];
    __shared__ float h1[256];
    __shared__ float h2[128];
    __shared__ float gl[64];
    int n = blockIdx.x / 96; int k = blockIdx.x % 96; int t = threadIdx.x;
    if (t < 192) a[t] = avec[n * 448 + t];
    {
        const float* p = x2 + ((size_t)(n * 256 + t)) * 16;
        float s = 0.0f;
        #pragma unroll
        for (int i = 0; i < 16; ++i) s += p[i];
        a[192 + t] = s * (1.0f / 16.0f);
    }
    __syncthreads();
    {
        float a0 = 0, a1 = 0, a2 = 0, a3 = 0;
        const float* wp = wf1 + (size_t)t * 448;
        for (int i = 0; i < 448; i += 4) {
            a0 = fmaf(wp[i], a[i], a0); a1 = fmaf(wp[i + 1], a[i + 1], a1);
            a2 = fmaf(wp[i + 2], a[i + 2], a2); a3 = fmaf(wp[i + 3], a[i + 3], a3);
        }
        h1[t] = fmaxf(a0 + a1 + a2 + a3 + bf1[t], 0.0f);
    }
    __syncthreads();
    if (t < 128) {
        float a0 = 0, a1 = 0, a2 = 0, a3 = 0;
        const float* wp = wf2 + (size_t)t * 256;
        for (int i = 0; i < 256; i += 4) {
            a0 = fmaf(wp[i], h1[i], a0); a1 = fmaf(wp[i + 1], h1[i + 1], a1);
            a2 = fmaf(wp[i + 2], h1[i + 2], a2); a3 = fmaf(wp[i + 3], h1[i + 3], a3);
        }
        h2[t] = fmaxf(a0 + a1 + a2 + a3 + bf2[t], 0.0f);
    }
    __syncthreads();
    if (t < 64) {
        float a0 = 0, a1 = 0, a2 = 0, a3 = 0;
        const float* wp = wf3 + (size_t)t * 128;
        for (int i = 0; i < 128; i += 4) {
            a0 = fmaf(wp[i], h2[i], a0); a1 = fmaf(wp[i + 1], h2[i + 1], a1);
            a2 = fmaf(wp[i + 2], h2[i + 2], a2); a3 = fmaf(wp[i + 3], h2[i + 3], a3);
        }
        gl[t] = fmaxf(a0 + a1 + a2 + a3 + bf3[t], 0.0f);
    }
    __syncthreads();
    float acc = blin[k];
    const float* wp = wlin + k * 64;
    const float* lo = local + (size_t)n * 64 * 256 + t;
    #pragma unroll 8
    for (int c = 0; c < 64; ++c)
        acc = fmaf(wp[c], fmaxf(gl[c] + lo[c * 256], 0.0f), acc);
    int ch = k >> 3; int z = k & 7;
    // z-innermost layout (R7)
    grid[(size_t)n * 24576 + (size_t)t * 96 + z * 12 + ch] = acc;
}

// ---- hdr v3: 1 pixel per thread (R7). Same math as v2; grid layout is
// z-innermost so each pixel reads 4 cell records, 2x48B contiguous each.
__global__ __launch_bounds__(256) void hdr_out_v3(
    const float* __restrict__ full, const float* __restrict__ low,
    const float* __restrict__ grid,
    const float* __restrict__ wgd1, const float* __restrict__ bgd1,
    const float* __restrict__ wgd2, const float* __restrict__ bgd2,
    const float* __restrict__ wau1, const float* __restrict__ bau1,
    const float* __restrict__ wau2, const float* __restrict__ bau2,
    const float* __restrict__ wav1, const float* __restrict__ bav1,
    const float* __restrict__ wav2, const float* __restrict__ bav2,
    float* __restrict__ out)
{
    int tid = blockIdx.x * 256 + threadIdx.x;
    int x = tid & 1023;
    int y = (tid >> 10) & 1023;
    int n = tid >> 20;
    const float* fp = full + ((size_t)n << 20);

    // 3x3 window around (y,x), zero-padded
    float v[3][3];
    #pragma unroll
    for (int r = 0; r < 3; ++r) {
        int yy = y + r - 1;
        bool okr = (unsigned)yy < 1024u;
        const float* row = fp + (size_t)yy * 1024;
        v[r][0] = (okr && x > 0)    ? row[x - 1] : 0.0f;
        v[r][1] = okr               ? row[x]     : 0.0f;
        v[r][2] = (okr && x < 1023) ? row[x + 1] : 0.0f;
    }

    // guide conv: 1->16 3x3 + relu, 16->1 1x1, tanh
    float gacc = bgd2[0];
    #pragma unroll
    for (int k = 0; k < 16; ++k) {
        const float* wk = wgd1 + k * 9;
        float h = bgd1[k];
        h = fmaf(wk[0], v[0][0], h); h = fmaf(wk[1], v[0][1], h); h = fmaf(wk[2], v[0][2], h);
        h = fmaf(wk[3], v[1][0], h); h = fmaf(wk[4], v[1][1], h); h = fmaf(wk[5], v[1][2], h);
        h = fmaf(wk[6], v[2][0], h); h = fmaf(wk[7], v[2][1], h); h = fmaf(wk[8], v[2][2], h);
        gacc = fmaf(wgd2[k], fmaxf(h, 0.0f), gacc);
    }
    float g = tanh_fast(gacc);

    // trilinear slice from bilateral grid
    float gxc = (x * (32.0f / 1023.0f) - 1.0f) * 0.5f;
    float gyc = (y * (32.0f / 1023.0f) - 1.0f) * 0.5f;
    float gzc = 4.0f * g + 3.5f;
    float x0f = floorf(gxc), y0f = floorf(gyc), z0f = floorf(gzc);
    float fx = gxc - x0f, fy = gyc - y0f, fz = gzc - z0f;
    int ix = (int)x0f, iy = (int)y0f, iz = (int)z0f;

    float wx0 = (ix >= 0 && ix < 16) ? (1.0f - fx) : 0.0f;
    float wx1 = (ix + 1 < 16) ? fx : 0.0f;
    float wy0 = (iy >= 0 && iy < 16) ? (1.0f - fy) : 0.0f;
    float wy1 = (iy + 1 < 16) ? fy : 0.0f;
    float wz0 = (iz >= 0 && iz < 8) ? (1.0f - fz) : 0.0f;
    float wz1 = (iz + 1 >= 0 && iz + 1 < 8) ? fz : 0.0f;
    int xi0 = min(max(ix, 0), 15), xi1 = min(ix + 1, 15);
    int yi0 = min(max(iy, 0), 15), yi1 = min(iy + 1, 15);
    int zi0 = min(max(iz, 0), 7),  zi1 = min(max(iz + 1, 0), 7);

    float w00 = wy0 * wx0, w01 = wy0 * wx1, w10 = wy1 * wx0, w11 = wy1 * wx1;

    const float* gb = grid + (size_t)n * 24576;
    const float* c00 = gb + (yi0 * 16 + xi0) * 96;
    const float* c01 = gb + (yi0 * 16 + xi1) * 96;
    const float* c10 = gb + (yi1 * 16 + xi0) * 96;
    const float* c11 = gb + (yi1 * 16 + xi1) * 96;
    int zo0 = zi0 * 12;
    int zo1 = zi1 * 12;

    float acc[12];
    #pragma unroll
    for (int i = 0; i < 12; ++i) acc[i] = 0.0f;

    #define CORNER(PTR, WK) { \
        const float4* q = (const float4*)(PTR); \
        float wk_ = (WK); \
        float4 A = q[0], B = q[1], C = q[2]; \
        acc[0] = fmaf(wk_, A.x, acc[0]); acc[1] = fmaf(wk_, A.y, acc[1]); \
        acc[2] = fmaf(wk_, A.z, acc[2]); acc[3] = fmaf(wk_, A.w, acc[3]); \
        acc[4] = fmaf(wk_, B.x, acc[4]); acc[5] = fmaf(wk_, B.y, acc[5]); \
        acc[6] = fmaf(wk_, B.z, acc[6]); acc[7] = fmaf(wk_, B.w, acc[7]); \
        acc[8] = fmaf(wk_, C.x, acc[8]); acc[9] = fmaf(wk_, C.y, acc[9]); \
        acc[10] = fmaf(wk_, C.z, acc[10]); acc[11] = fmaf(wk_, C.w, acc[11]); }

    CORNER(c00 + zo0, wz0 * w00)
    CORNER(c01 + zo0, wz0 * w01)
    CORNER(c10 + zo0, wz0 * w10)
    CORNER(c11 + zo0, wz0 * w11)
    CORNER(c00 + zo1, wz1 * w00)
    CORNER(c01 + zo1, wz1 * w01)
    CORNER(c10 + zo1, wz1 * w10)
    CORNER(c11 + zo1, wz1 * w11)
    #undef CORNER

    float p = v[1][1];
    float Yv = fmaf(p, acc[3],  acc[0] + acc[1] + acc[2]);
    float U0 = fmaf(p, acc[7],  acc[4] + acc[5] + acc[6]);
    float V0 = fmaf(p, acc[11], acc[8] + acc[9] + acc[10]);

    float uacc = bau2[0];
    #pragma unroll
    for (int k = 0; k < 16; ++k)
        uacc = fmaf(wau2[k], fmaxf(fmaf(wau1[k], U0, bau1[k]), 0.0f), uacc);
    float vacc = bav2[0];
    #pragma unroll
    for (int k = 0; k < 16; ++k)
        vacc = fmaf(wav2[k], fmaxf(fmaf(wav1[k], V0, bav1[k]), 0.0f), vacc);

    // fake = bilinear upsample of low-res (channels 1,2)
    float sx = (x + 0.5f) * 0.25f - 0.5f;
    float sy = (y + 0.5f) * 0.25f - 0.5f;
    float sxf = floorf(sx), syf = floorf(sy);
    float fxl = sx - sxf, fyl = sy - syf;
    int jx0 = max((int)sxf, 0), jx1 = min((int)sxf + 1, 255);
    int jy0 = max((int)syf, 0), jy1 = min((int)syf + 1, 255);
    const float* lr1 = low + ((size_t)(n * 3 + 1)) * 65536;
    const float* lr2 = low + ((size_t)(n * 3 + 2)) * 65536;
    float f1 = (1.0f - fyl) * ((1.0f - fxl) * lr1[jy0 * 256 + jx0] + fxl * lr1[jy0 * 256 + jx1])
             + fyl * ((1.0f - fxl) * lr1[jy1 * 256 + jx0] + fxl * lr1[jy1 * 256 + jx1]);
    float f2 = (1.0f - fyl) * ((1.0f - fxl) * lr2[jy0 * 256 + jx0] + fxl * lr2[jy0 * 256 + jx1])
             + fyl * ((1.0f - fxl) * lr2[jy1 * 256 + jx0] + fxl * lr2[jy1 * 256 + jx1]);

    float Uv = tanh_fast(uacc) + f1;
    float Vv = tanh_fast(vacc) + f2;

    size_t base = ((size_t)n * 3) * 1048576 + (size_t)y * 1024 + x;
    out[base]            = Yv;
    out[base + 1048576]  = Uv;
    out[base + 2097152]  = Vv;
}

extern "C" void kernel_launch(void* const* d_in, const int* in_sizes, int n_in,
                              void* d_out, int out_size, void* d_ws, size_t ws_size,
                              hipStream_t stream)
{
    const float* low  = (const float*)d_in[0];
    const float* full = (const float*)d_in[1];
    const float* w0 = (const float*)d_in[2];  const float* b0 = (const float*)d_in[3];
    const float* w1 = (const float*)d_in[4];  const float* b1 = (const float*)d_in[5];
    const float* w2 = (const float*)d_in[6];  const float* b2 = (const float*)d_in[7];
    const float* w3 = (const float*)d_in[8];  const float* b3 = (const float*)d_in[9];
    const float* wl0 = (const float*)d_in[10]; const float* bl0 = (const float*)d_in[11];
    const float* wl1 = (const float*)d_in[12];
    const float* wg1 = (const float*)d_in[13]; const float* bg1 = (const float*)d_in[14];
    const float* wg2 = (const float*)d_in[15]; const float* bg2 = (const float*)d_in[16];
    const float* wf1 = (const float*)d_in[17]; const float* bf1 = (const float*)d_in[18];
    const float* wf2 = (const float*)d_in[19]; const float* bf2 = (const float*)d_in[20];
    const float* wf3 = (const float*)d_in[21]; const float* bf3 = (const float*)d_in[22];
    const float* wlin = (const float*)d_in[23]; const float* blin = (const float*)d_in[24];
    const float* wgd1 = (const float*)d_in[25]; const float* bgd1 = (const float*)d_in[26];
    const float* wgd2 = (const float*)d_in[27]; const float* bgd2 = (const float*)d_in[28];
    const float* wau1 = (const float*)d_in[29]; const float* bau1 = (const float*)d_in[30];
    const float* wau2 = (const float*)d_in[31]; const float* bau2 = (const float*)d_in[32];
    const float* wav1 = (const float*)d_in[33]; const float* bav1 = (const float*)d_in[34];
    const float* wav2 = (const float*)d_in[35]; const float* bav2 = (const float*)d_in[36];
    float* out = (float*)d_out;

    float* ws = (float*)d_ws;
    float* t0b    = ws;
    float* t1b    = t0b + 524288;
    float* t2b    = t1b + 262144;
    float* splat  = t2b + 131072;
    float* l0o    = splat + 65536;
    float* localb = l0o + 65536;
    float* x1b    = localb + 65536;
    float* x2b    = x1b + 32768;
    float* avec   = x2b + 16384;
    float* gridb  = avec + 1792;

    conv_s2_small<3, 8, 256, 256, 128, 128><<<2048, 256, 0, stream>>>(low, w0, b0, t0b);
    conv_s2_small<8, 16, 128, 128, 64, 64><<<1024, 256, 0, stream>>>(t0b, w1, b1, t1b);
    conv2_k<<<2048, 256, 0, stream>>>(t1b, w2, b2, t2b);
    conv3_k<<<2048, 256, 0, stream>>>(t2b, w3, b3, splat);
    k5_l0_g1_means<<<6208, 256, 0, stream>>>(splat, wl0, bl0, l0o, wg1, bg1, x1b, avec);
    k6_l1_g2_means<<<5248, 256, 0, stream>>>(l0o, wl1, localb, x1b, wg2, bg2, x2b, avec);
    kfc_fuse<<<384, 256, 0, stream>>>(avec, x2b, wf1, bf1, wf2, bf2, wf3, bf3,
                                      localb, wlin, blin, gridb);
    hdr_out_v3<<<16384, 256, 0, stream>>>(full, low, gridb,
        wgd1, bgd1, wgd2, bgd2, wau1, bau1, wau2, bau2, wav1, bav1, wav2, bav2, out);
}